// Round 12
// baseline (70.406 us; speedup 1.0000x reference)
//
#include <hip/hip_runtime.h>

// LocallyConnected3D: out[b,l,f] = sum_p patch[b,l,p] * W[l,p,f] + bias[l,f]
// W = (27000,216,16) f32 = 373 MB streamed once -> HBM-bound.
// R12 = R11 with 8 waves per block (512 thr), grid 27000/8 = 3375 —
// further amortizing WG dispatch overhead (R10->R11 showed ~5.3us of it).
// Still barrier-free (per-wave LDS regions). Weight stream nontemporal.

#define LLOC 27000
#define PDIM 216
#define FDIM 16
#define CIN 8

typedef float f32x2 __attribute__((ext_vector_type(2)));

__global__ __launch_bounds__(512) void lc3d_kernel(
    const float* __restrict__ x,
    const float* __restrict__ w,
    const float* __restrict__ bias,
    float* __restrict__ out)
{
    const int wid  = threadIdx.x >> 6;  // wave 0..7
    const int lane = threadIdx.x & 63;
    const int l = blockIdx.x * 8 + wid;
    const int od = l / 900;
    const int rl = l - od * 900;
    const int oh = rl / 30;
    const int ow = rl - oh * 30;

    __shared__ float patch[8][4 * PDIM];   // [wave][b*PDIM + p]
    float* mypatch = patch[wid];

    // ---- Phase 1a: issue x gather loads into registers ----
    float4 xv[4];
    int ldst[4];
    #pragma unroll
    for (int i = 0; i < 4; ++i) {
        const int idx   = i * 64 + lane;        // 0..255, 216 real chunks
        const bool vld  = idx < 216;
        const int cidx  = vld ? idx : 0;
        const int b     = cidx / 54;            // 54 float4 per batch
        const int r     = cidx - b * 54;
        const int slab  = r >> 1;               // kd*9 + kh*3 + kw
        const int half  = r & 1;
        const int kd    = slab / 9;
        const int r2    = slab - kd * 9;
        const int kh    = r2 / 3;
        const int kw    = r2 - kh * 3;
        ldst[i] = vld ? (b * PDIM + slab * 8 + half * 4) : -1;
        xv[i] = *reinterpret_cast<const float4*>(
            x + ((((b * 32 + od + kd) * 32 + (oh + kh)) * 32 + (ow + kw)) * CIN
                 + half * 4));
    }

    // ---- Phase 1b: weight stream (27 x 512B/wave), nontemporal ----
    const int pidx = lane >> 3;                 // p % 8   (== input channel c)
    const int fh   = lane & 7;                  // f pair index
    const f32x2* wbase =
        reinterpret_cast<const f32x2*>(w + (size_t)l * (PDIM * FDIM));
    f32x2 wr[27];
    #pragma unroll
    for (int i = 0; i < 27; ++i)
        wr[i] = __builtin_nontemporal_load(wbase + i * 64 + lane);

    // ---- Phase 1c: write patch to LDS (waits only on the older x loads;
    //      weight loads remain outstanding in the vmcnt FIFO) ----
    #pragma unroll
    for (int i = 0; i < 4; ++i)
        if (ldst[i] >= 0)
            *reinterpret_cast<float4*>(&mypatch[ldst[i]]) = xv[i];

    // ---- Phase 2: FMA; progressive vmcnt per wr[i] ----
    float acc[4][2] = {};
    #pragma unroll
    for (int i = 0; i < 27; ++i) {
        const int p = i * 8 + pidx;
        #pragma unroll
        for (int b = 0; b < 4; ++b) {
            const float pv = mypatch[b * PDIM + p];   // LDS broadcast, conflict-free
            acc[b][0] = fmaf(pv, wr[i].x, acc[b][0]);
            acc[b][1] = fmaf(pv, wr[i].y, acc[b][1]);
        }
    }

    // ---- Phase 3: reduce across the 8 pidx groups ----
    #pragma unroll
    for (int b = 0; b < 4; ++b) {
        #pragma unroll
        for (int j = 0; j < 2; ++j) {
            float v = acc[b][j];
            v += __shfl_xor(v, 8, 64);
            v += __shfl_xor(v, 16, 64);
            v += __shfl_xor(v, 32, 64);
            acc[b][j] = v;
        }
    }

    // ---- Epilogue: lanes 0..7 hold full sums; write all 4 batches ----
    if (pidx == 0) {
        const float2 bv =
            *reinterpret_cast<const float2*>(bias + l * FDIM + fh * 2);
        #pragma unroll
        for (int b = 0; b < 4; ++b) {
            float2 o;
            o.x = acc[b][0] + bv.x;
            o.y = acc[b][1] + bv.y;
            *reinterpret_cast<float2*>(
                out + ((size_t)b * LLOC + l) * FDIM + fh * 2) = o;
        }
    }
}

extern "C" void kernel_launch(void* const* d_in, const int* in_sizes, int n_in,
                              void* d_out, int out_size, void* d_ws, size_t ws_size,
                              hipStream_t stream) {
    const float* x    = (const float*)d_in[0];
    const float* wgt  = (const float*)d_in[1];
    const float* bias = (const float*)d_in[2];
    float* out        = (float*)d_out;

    lc3d_kernel<<<dim3(LLOC / 8), dim3(512), 0, stream>>>(x, wgt, bias, out);
}

// Round 13
// 64.841 us; speedup vs baseline: 1.0858x; 1.0858x over previous
//
#include <hip/hip_runtime.h>

// LocallyConnected3D: out[b,l,f] = sum_p patch[b,l,p] * W[l,p,f] + bias[l,f]
// W = (27000,216,16) f32 = 373 MB streamed once -> HBM-bound.
// R13 = R11 (best, 66.8us: 4 waves/block, barrier-free, nt weights)
//   + bijective XCD-aware block swizzle (m204): each XCD gets a contiguous
//   chunk of ~844 blocks so its x working slab stays L2-resident instead of
//   every XCD re-fetching all of x through the weight-flushed L3.

#define LLOC 27000
#define PDIM 216
#define FDIM 16
#define CIN 8
#define NWG  (LLOC / 4)   // 6750
#define NXCD 8

typedef float f32x2 __attribute__((ext_vector_type(2)));

__global__ __launch_bounds__(256) void lc3d_kernel(
    const float* __restrict__ x,
    const float* __restrict__ w,
    const float* __restrict__ bias,
    float* __restrict__ out)
{
    // ---- bijective XCD swizzle (nwg=6750, q=843, r=6): physical blockIdx
    // round-robins XCDs; remap so each XCD owns a contiguous logical range.
    const int orig = blockIdx.x;
    const int xcd  = orig & (NXCD - 1);       // orig % 8
    const int seq  = orig >> 3;               // orig / 8
    const int q    = NWG / NXCD;              // 843
    const int r    = NWG % NXCD;              // 6
    const int base = (xcd < r) ? xcd * (q + 1) : r * (q + 1) + (xcd - r) * q;
    const int wgid = base + seq;

    const int wid  = threadIdx.x >> 6;  // wave 0..3
    const int lane = threadIdx.x & 63;
    const int l = wgid * 4 + wid;
    const int od = l / 900;
    const int rl = l - od * 900;
    const int oh = rl / 30;
    const int ow = rl - oh * 30;

    __shared__ float patch[4][4 * PDIM];   // [wave][b*PDIM + p]
    float* mypatch = patch[wid];

    // ---- Phase 1a: issue x gather loads into registers ----
    float4 xv[4];
    int ldst[4];
    #pragma unroll
    for (int i = 0; i < 4; ++i) {
        const int idx   = i * 64 + lane;        // 0..255, 216 real chunks
        const bool vld  = idx < 216;
        const int cidx  = vld ? idx : 0;
        const int b     = cidx / 54;            // 54 float4 per batch
        const int rr    = cidx - b * 54;
        const int slab  = rr >> 1;              // kd*9 + kh*3 + kw
        const int half  = rr & 1;
        const int kd    = slab / 9;
        const int r2    = slab - kd * 9;
        const int kh    = r2 / 3;
        const int kw    = r2 - kh * 3;
        ldst[i] = vld ? (b * PDIM + slab * 8 + half * 4) : -1;
        xv[i] = *reinterpret_cast<const float4*>(
            x + ((((b * 32 + od + kd) * 32 + (oh + kh)) * 32 + (ow + kw)) * CIN
                 + half * 4));
    }

    // ---- Phase 1b: weight stream (27 x 512B/wave), nontemporal ----
    const int pidx = lane >> 3;                 // p % 8   (== input channel c)
    const int fh   = lane & 7;                  // f pair index
    const f32x2* wbase =
        reinterpret_cast<const f32x2*>(w + (size_t)l * (PDIM * FDIM));
    f32x2 wr[27];
    #pragma unroll
    for (int i = 0; i < 27; ++i)
        wr[i] = __builtin_nontemporal_load(wbase + i * 64 + lane);

    // ---- Phase 1c: write patch to LDS (waits only on the older x loads;
    //      weight loads remain outstanding in the vmcnt FIFO) ----
    #pragma unroll
    for (int i = 0; i < 4; ++i)
        if (ldst[i] >= 0)
            *reinterpret_cast<float4*>(&mypatch[ldst[i]]) = xv[i];

    // ---- Phase 2: FMA; progressive vmcnt per wr[i] ----
    float acc[4][2] = {};
    #pragma unroll
    for (int i = 0; i < 27; ++i) {
        const int p = i * 8 + pidx;
        #pragma unroll
        for (int b = 0; b < 4; ++b) {
            const float pv = mypatch[b * PDIM + p];   // LDS broadcast, conflict-free
            acc[b][0] = fmaf(pv, wr[i].x, acc[b][0]);
            acc[b][1] = fmaf(pv, wr[i].y, acc[b][1]);
        }
    }

    // ---- Phase 3: reduce across the 8 pidx groups ----
    #pragma unroll
    for (int b = 0; b < 4; ++b) {
        #pragma unroll
        for (int j = 0; j < 2; ++j) {
            float v = acc[b][j];
            v += __shfl_xor(v, 8, 64);
            v += __shfl_xor(v, 16, 64);
            v += __shfl_xor(v, 32, 64);
            acc[b][j] = v;
        }
    }

    // ---- Epilogue: lanes 0..7 hold full sums; write all 4 batches ----
    if (pidx == 0) {
        const float2 bv =
            *reinterpret_cast<const float2*>(bias + l * FDIM + fh * 2);
        #pragma unroll
        for (int b = 0; b < 4; ++b) {
            float2 o;
            o.x = acc[b][0] + bv.x;
            o.y = acc[b][1] + bv.y;
            *reinterpret_cast<float2*>(
                out + ((size_t)b * LLOC + l) * FDIM + fh * 2) = o;
        }
    }
}

extern "C" void kernel_launch(void* const* d_in, const int* in_sizes, int n_in,
                              void* d_out, int out_size, void* d_ws, size_t ws_size,
                              hipStream_t stream) {
    const float* x    = (const float*)d_in[0];
    const float* wgt  = (const float*)d_in[1];
    const float* bias = (const float*)d_in[2];
    float* out        = (float*)d_out;

    lc3d_kernel<<<dim3(NWG), dim3(256), 0, stream>>>(x, wgt, bias, out);
}